// Round 1
// baseline (90.509 us; speedup 1.0000x reference)
//
#include <hip/hip_runtime.h>
#include <hip/hip_bf16.h>
#include <stdint.h>

// Head fused kernel: q,k,v = x@W{q,k,v}; causal softmax(q k^T / 32) @ v
// B=128 T=256 C=1024 H=128.
// ws layout: Wt bf16 [384][1024] | q bf16 [32768][128] | k bf16 [32768][128] | vT bf16 [128][128][256]
// total ws use = 786432 + 3*8388608 = 25952256 bytes.

typedef __attribute__((ext_vector_type(4))) float  floatx4;
typedef __attribute__((ext_vector_type(4))) float  float4v;
typedef __attribute__((ext_vector_type(8))) short  short8;
typedef __attribute__((ext_vector_type(4))) short  short4v;

__device__ __forceinline__ short f2bf(float f) {
  unsigned u = __builtin_bit_cast(unsigned, f);
  unsigned r = (u + 0x7FFFu + ((u >> 16) & 1u)) >> 16;   // RNE
  return (short)(unsigned short)r;
}

// ---------------- kernel 1: W transpose + bf16 convert --------------------
// Wt[n][c]: n in [0,128)->Wq col n ; [128,256)->Wk ; [256,384)->Wv
__global__ void wconv_kernel(const float* __restrict__ Wk, const float* __restrict__ Wq,
                             const float* __restrict__ Wv, short* __restrict__ Wt) {
  int n = blockIdx.x;
  const float* W = (n < 128) ? Wq : ((n < 256) ? Wk : Wv);
  int col = n & 127;
  int base = n << 10;
  for (int c = threadIdx.x; c < 1024; c += blockDim.x)
    Wt[base + c] = f2bf(W[(c << 7) + col]);
}

// ---------------- kernel 2: projection GEMM -------------------------------
// C[m][n] = sum_c xbf[m][c] * Wt[n][c],  m-tile 64, n = all 384, BK=64.
// 256 threads = 4 waves; wave wv owns n in [wv*96, wv*96+96): 4x6 16x16 frags.
__global__ __launch_bounds__(256, 2) void proj_kernel(
    const float* __restrict__ x, const short* __restrict__ Wt,
    short* __restrict__ qb, short* __restrict__ kb, short* __restrict__ vT) {
  __shared__ short As[64 * 64];    // [row][k] bf16, XOR-swizzled rows (128B rows)
  __shared__ short Bs[384 * 64];   // [n][k]  bf16, XOR-swizzled
  const int tid  = threadIdx.x;
  const int lane = tid & 63;
  const int wv   = tid >> 6;
  const int m0   = blockIdx.x << 6;

  const floatx4 fz = {0.f, 0.f, 0.f, 0.f};
  floatx4 acc[4][6];
#pragma unroll
  for (int a = 0; a < 4; ++a)
#pragma unroll
    for (int bb = 0; bb < 6; ++bb) acc[a][bb] = fz;

  for (int kt = 0; kt < 16; ++kt) {
    const int k0 = kt << 6;
    __syncthreads();
    // stage A: 64x64 fp32 -> bf16 (swizzled)
#pragma unroll
    for (int it = 0; it < 4; ++it) {
      int idx = it * 256 + tid;
      int row = idx >> 4, c4 = idx & 15;
      const float4v xv =
          *reinterpret_cast<const float4v*>(x + (size_t)(m0 + row) * 1024 + k0 + (c4 << 2));
      short4v h;
      h[0] = f2bf(xv[0]); h[1] = f2bf(xv[1]); h[2] = f2bf(xv[2]); h[3] = f2bf(xv[3]);
      int pb = (row << 7) + (((c4 << 3)) ^ ((row & 7) << 4));
      *reinterpret_cast<short4v*>(reinterpret_cast<char*>(As) + pb) = h;
    }
    // stage B: 384x64 bf16 (swizzled)
#pragma unroll
    for (int it = 0; it < 12; ++it) {
      int idx = it * 256 + tid;
      int row = idx >> 3, c8 = idx & 7;
      const short8 w8 =
          *reinterpret_cast<const short8*>(Wt + (size_t)row * 1024 + k0 + (c8 << 3));
      int pb = (row << 7) + (((c8 << 4)) ^ ((row & 7) << 4));
      *reinterpret_cast<short8*>(reinterpret_cast<char*>(Bs) + pb) = w8;
    }
    __syncthreads();
    // compute: 2 k-steps of 32, 24 MFMA each
#pragma unroll
    for (int ks = 0; ks < 2; ++ks) {
      short8 af[4], bf[6];
#pragma unroll
      for (int mf = 0; mf < 4; ++mf) {
        int row = (mf << 4) + (lane & 15);
        int pb = (row << 7) + ((((ks << 6) + ((lane >> 4) << 4))) ^ ((row & 7) << 4));
        af[mf] = *reinterpret_cast<const short8*>(reinterpret_cast<const char*>(As) + pb);
      }
#pragma unroll
      for (int nf = 0; nf < 6; ++nf) {
        int n = wv * 96 + (nf << 4) + (lane & 15);
        int pb = (n << 7) + ((((ks << 6) + ((lane >> 4) << 4))) ^ ((n & 7) << 4));
        bf[nf] = *reinterpret_cast<const short8*>(reinterpret_cast<const char*>(Bs) + pb);
      }
#pragma unroll
      for (int mf = 0; mf < 4; ++mf)
#pragma unroll
        for (int nf = 0; nf < 6; ++nf)
          acc[mf][nf] =
              __builtin_amdgcn_mfma_f32_16x16x32_bf16(af[mf], bf[nf], acc[mf][nf], 0, 0, 0);
    }
  }
  // epilogue: C/D layout col=lane&15, row=(lane>>4)*4+r
#pragma unroll
  for (int mf = 0; mf < 4; ++mf) {
#pragma unroll
    for (int nf = 0; nf < 6; ++nf) {
#pragma unroll
      for (int r = 0; r < 4; ++r) {
        int m = m0 + (mf << 4) + ((lane >> 4) << 2) + r;
        int n = wv * 96 + (nf << 4) + (lane & 15);
        short bv = f2bf(acc[mf][nf][r]);
        int h = n & 127;
        if (n < 128)      qb[(size_t)m * 128 + h] = bv;
        else if (n < 256) kb[(size_t)m * 128 + h] = bv;
        else              vT[((size_t)(m >> 8) << 15) + (h << 8) + (m & 255)] = bv;
      }
    }
  }
}

// ---------------- kernel 3: causal attention ------------------------------
// 1 wave per block, 16 q-rows; kv tiles of 64; no-max softmax (logits |s|<~1).
__global__ __launch_bounds__(64, 2) void attn_kernel(
    const short* __restrict__ q, const short* __restrict__ k,
    const short* __restrict__ vT, float* __restrict__ out) {
  __shared__ short P[16 * 64];   // swizzled
  const int lane = threadIdx.x;
  const int b    = blockIdx.x >> 4;
  const int w    = blockIdx.x & 15;
  const int qr0  = w << 4;
  const short* qb = q  + ((size_t)b << 15);
  const short* kb = k  + ((size_t)b << 15);
  const short* vb = vT + ((size_t)b << 15);

  short8 qf[4];
  {
    int row = qr0 + (lane & 15);
#pragma unroll
    for (int hs = 0; hs < 4; ++hs)
      qf[hs] = *reinterpret_cast<const short8*>(qb + row * 128 + (hs << 5) + ((lane >> 4) << 3));
  }
  const floatx4 fz = {0.f, 0.f, 0.f, 0.f};
  floatx4 o[8];
#pragma unroll
  for (int i = 0; i < 8; ++i) o[i] = fz;
  float ls[4] = {0.f, 0.f, 0.f, 0.f};

  const int nt = ((w << 4) + 79) >> 6;   // tiles needed to reach row qr0+15
  for (int tt = 0; tt < nt; ++tt) {
    const int j0 = tt << 6;
    floatx4 s[4];
#pragma unroll
    for (int i = 0; i < 4; ++i) s[i] = fz;
    // S = Q K^T  (16x64 over h=128)
#pragma unroll
    for (int nf = 0; nf < 4; ++nf) {
      int kr = j0 + (nf << 4) + (lane & 15);
#pragma unroll
      for (int hs = 0; hs < 4; ++hs) {
        short8 kf =
            *reinterpret_cast<const short8*>(kb + kr * 128 + (hs << 5) + ((lane >> 4) << 3));
        s[nf] = __builtin_amdgcn_mfma_f32_16x16x32_bf16(qf[hs], kf, s[nf], 0, 0, 0);
      }
    }
    // mask + exp (no max needed: |s*scale| <~ 1), write P to swizzled LDS
    const int ib = qr0 + ((lane >> 4) << 2);
#pragma unroll
    for (int nf = 0; nf < 4; ++nf) {
      int j = j0 + (nf << 4) + (lane & 15);
#pragma unroll
      for (int r = 0; r < 4; ++r) {
        float p = (j <= ib + r) ? __expf(s[nf][r] * 0.03125f) : 0.f;
        ls[r] += p;
        int prow = ((lane >> 4) << 2) + r;
        int pb = (prow << 7) + (((((nf << 4) + (lane & 15)) << 1)) ^ ((prow & 7) << 4));
        *reinterpret_cast<short*>(reinterpret_cast<char*>(P) + pb) = f2bf(p);
      }
    }
    __syncthreads();
    // reload P as A-operand frags
    short8 pa[2];
#pragma unroll
    for (int ks = 0; ks < 2; ++ks) {
      int prow = lane & 15;
      int pb = (prow << 7) + ((((ks << 6) + ((lane >> 4) << 4))) ^ ((prow & 7) << 4));
      pa[ks] = *reinterpret_cast<const short8*>(reinterpret_cast<const char*>(P) + pb);
    }
    // O += P V  (V read via vT, contiguous)
#pragma unroll
    for (int hf = 0; hf < 8; ++hf) {
#pragma unroll
      for (int ks = 0; ks < 2; ++ks) {
        int vrow = (hf << 4) + (lane & 15);
        short8 vf = *reinterpret_cast<const short8*>(vb + (vrow << 8) + j0 + (ks << 5) +
                                                     ((lane >> 4) << 3));
        o[hf] = __builtin_amdgcn_mfma_f32_16x16x32_bf16(pa[ks], vf, o[hf], 0, 0, 0);
      }
    }
    __syncthreads();
  }
  // row-sum reduce across the 16-lane group, then normalize + store
#pragma unroll
  for (int r = 0; r < 4; ++r) {
#pragma unroll
    for (int mk = 1; mk < 16; mk <<= 1) ls[r] += __shfl_xor(ls[r], mk);
  }
#pragma unroll
  for (int r = 0; r < 4; ++r) {
    float inv = 1.0f / ls[r];
    int t = qr0 + ((lane >> 4) << 2) + r;
#pragma unroll
    for (int hf = 0; hf < 8; ++hf)
      out[(((size_t)b << 8) + t) * 128 + (hf << 4) + (lane & 15)] = o[hf][r] * inv;
  }
}

extern "C" void kernel_launch(void* const* d_in, const int* in_sizes, int n_in,
                              void* d_out, int out_size, void* d_ws, size_t ws_size,
                              hipStream_t stream) {
  const float* x  = (const float*)d_in[0];
  const float* Wk = (const float*)d_in[1];
  const float* Wq = (const float*)d_in[2];
  const float* Wv = (const float*)d_in[3];
  float* out = (float*)d_out;

  char* ws = (char*)d_ws;
  short* Wt = (short*)ws;                                   // 384*1024*2 = 786432 B
  short* qb = (short*)(ws + 786432);                        // 8388608 B
  short* kb = (short*)(ws + 786432 + 8388608);              // 8388608 B
  short* vT = (short*)(ws + 786432 + 2 * 8388608);          // 8388608 B

  wconv_kernel<<<384, 256, 0, stream>>>(Wk, Wq, Wv, Wt);
  proj_kernel<<<512, 256, 0, stream>>>(x, Wt, qb, kb, vT);
  attn_kernel<<<128 * 16, 64, 0, stream>>>(qb, kb, vT, out);
}